// Round 4
// baseline (327.783 us; speedup 1.0000x reference)
//
#include <hip/hip_runtime.h>
#include <hip/hip_bf16.h>

#define HH 8
#define DD 64
#define NN 256
#define Q1c 21
#define Q2c 21
#define MM 4096
#define KTOT 2048   // HH*NN
#define BN 64

typedef __attribute__((ext_vector_type(8))) short short8;
typedef __attribute__((ext_vector_type(4))) float f32x4;
typedef __attribute__((ext_vector_type(16))) float f32x16;
typedef __attribute__((ext_vector_type(4))) unsigned int u32x4;

__device__ inline unsigned short f2bf(float f) {
  __hip_bfloat16 h = __float2bfloat16(f);
  return *reinterpret_cast<unsigned short*>(&h);
}

// Kernel 0: pack Z2 (int32 [j][m]) -> Z2t bytes [j/8][m][8] so k_gemm loads
// 8 indices with one dwordx2.
__global__ void k_pack(const int* __restrict__ Z2, unsigned char* __restrict__ Z2t) {
  int jb = blockIdx.x >> 4;                       // 0..31
  int m  = ((blockIdx.x & 15) << 8) + threadIdx.x;
  unsigned lo = 0, hi = 0;
#pragma unroll
  for (int r = 0; r < 4; ++r) lo |= ((unsigned)Z2[(jb*8 + r)*MM + m] & 255u) << (8*r);
#pragma unroll
  for (int r = 0; r < 4; ++r) hi |= ((unsigned)Z2[(jb*8 + 4 + r)*MM + m] & 255u) << (8*r);
  uint2 v; v.x = lo; v.y = hi;
  *reinterpret_cast<uint2*>(Z2t + ((size_t)jb*MM + m)*8) = v;
}

// Kernel 1: e = Q^T K per head, softmax over j. Writes sf (f32 [h][i][j]) and
// sfF: bf16 A-operand pre-fragmented as [ks=k/32][i][k%32].
__global__ void k_softmax(const float* __restrict__ Q, const float* __restrict__ K,
                          float* __restrict__ sf, unsigned short* __restrict__ sfF) {
  int h = blockIdx.x >> 8;
  int i = blockIdx.x & 255;
  int j = threadIdx.x;
  __shared__ float qs[DD];
  __shared__ float red[4];
  if (j < DD) qs[j] = Q[(h*DD + j)*NN + i];
  __syncthreads();
  float e = 0.f;
#pragma unroll
  for (int d = 0; d < DD; ++d) e = fmaf(qs[d], K[(h*DD + d)*NN + j], e);
  float mx = e;
#pragma unroll
  for (int o = 32; o; o >>= 1) mx = fmaxf(mx, __shfl_xor(mx, o));
  if ((j & 63) == 0) red[j >> 6] = mx;
  __syncthreads();
  mx = fmaxf(fmaxf(red[0], red[1]), fmaxf(red[2], red[3]));
  float p = __expf(e - mx);
  float s = p;
#pragma unroll
  for (int o = 32; o; o >>= 1) s += __shfl_xor(s, o);
  __syncthreads();
  if ((j & 63) == 0) red[j >> 6] = s;
  __syncthreads();
  s = red[0] + red[1] + red[2] + red[3];
  p = p / s;
  sf[(h*NN + i)*NN + j] = p;
  int ks = h*8 + (j >> 5);
  sfF[((ks*NN + i) << 5) + (j & 31)] = f2bf(p);
}

// Kernel 2: Mmat[h,k] upper-tri 36 entries via atomics.
__global__ void k_mmat(const float* __restrict__ sf, float* __restrict__ Mmat) {
  int i = blockIdx.x, j = threadIdx.x;
  float v[HH];
#pragma unroll
  for (int h = 0; h < HH; ++h) v[h] = sf[(h*NN + i)*NN + j];
  float pr[36];
  {
    int idx = 0;
#pragma unroll
    for (int h = 0; h < HH; ++h)
#pragma unroll
      for (int k = h; k < HH; ++k) pr[idx++] = v[h]*v[k];
  }
#pragma unroll
  for (int x = 0; x < 36; ++x) {
#pragma unroll
    for (int o = 32; o; o >>= 1) pr[x] += __shfl_xor(pr[x], o);
  }
  __shared__ float mm[4][36];
  int w = j >> 6;
  if ((j & 63) == 0) {
#pragma unroll
    for (int x = 0; x < 36; ++x) mm[w][x] = pr[x];
  }
  __syncthreads();
  if (j < 36) atomicAdd(&Mmat[j], mm[0][j] + mm[1][j] + mm[2][j] + mm[3][j]);
}

// Kernel 3: big GEMM, barrier-free. 2 waves x (128 rows x 64 cols), MFMA
// 32x32x16. Each wave gathers its OWN B fragments via ds_bpermute from a
// V-row pair held in lane registers (heads 2hp/2hp+1 packed lo/hi, same Z2
// indices). A fragments stream from global sfF (L2-resident). No LDS, no
// barriers: DS(bperm) / MFMA / VMEM pipes overlap freely across waves.
__global__ __launch_bounds__(128, 2) void k_gemm(
    const unsigned short* __restrict__ sfF, const float* __restrict__ Vf,
    const int* __restrict__ Z1, const unsigned char* __restrict__ Z2t,
    float* __restrict__ Sexp, float* __restrict__ Ene) {
  const int t  = threadIdx.x;
  const int w  = t >> 6;          // 0..1
  const int l  = t & 63;
  const int lc = l & 31;          // col (B/C) or row (A) lane index
  const int lo = l >> 5;          // k-octet selector

  const int n0 = blockIdx.x * BN;
  const int a_blk = n0 / MM;      // 0..20 (64 | 4096)
  const int m0 = n0 - a_blk * MM;
  const int wrow = w * 128;

  f32x16 acc[4][2];               // [mr][ct]
#pragma unroll
  for (int mr = 0; mr < 4; ++mr)
#pragma unroll
    for (int ct = 0; ct < 2; ++ct)
#pragma unroll
      for (int r = 0; r < 16; ++r) acc[mr][ct][r] = 0.f;

  // per-lane invariant addresses
  const unsigned char* zrow0 = Z2t + ((size_t)(m0 + lc)) * 8;          // +ct*32*8
  const unsigned short* arow = sfF + (((size_t)(wrow + lc)) << 5) + lo*8; // +ks*NN*32 + mr*32*32 + kstep*16

  for (int hp = 0; hp < 4; ++hp) {
    // V pair for this head pair: lane c<21 holds (V[2hp+1][a][c]<<16)|V[2hp][a][c]
    float va = (l < Q1c) ? Vf[(2*hp    )*(Q1c*Q2c) + a_blk*Q2c + l] : 0.f;
    float vb = (l < Q1c) ? Vf[(2*hp + 1)*(Q1c*Q2c) + a_blk*Q2c + l] : 0.f;
    const int vcur = (int)(((unsigned)f2bf(vb) << 16) | (unsigned)f2bf(va));

#pragma unroll
    for (int js = 0; js < 8; ++js) {
      // ---- Z2 index bytes for this superstep: z[kstep][ct] ----
      uint2 z[2][2];
#pragma unroll
      for (int ks2 = 0; ks2 < 2; ++ks2)
#pragma unroll
        for (int ct = 0; ct < 2; ++ct) {
          int jb = js*4 + ks2*2 + lo;
          z[ks2][ct] = *reinterpret_cast<const uint2*>(zrow0 + ((size_t)jb*MM + ct*32) * 8);
        }
#pragma unroll
      for (int ks2 = 0; ks2 < 2; ++ks2) {
        // ---- A fragments for this kstep: af[head][mr] ----
        short8 af[2][4];
#pragma unroll
        for (int th = 0; th < 2; ++th) {
          const unsigned short* ab = arow + ((size_t)((2*hp + th)*8 + js) * NN) * 32 + ks2*16;
#pragma unroll
          for (int mr = 0; mr < 4; ++mr)
            af[th][mr] = *reinterpret_cast<const short8*>(ab + mr*32*32);
        }
        // ---- gather B (both col-tiles), both heads packed, then MFMA ----
#pragma unroll
        for (int ct = 0; ct < 2; ++ct) {
          unsigned zlo = z[ks2][ct].x, zhi = z[ks2][ct].y;
          unsigned g[8];
#pragma unroll
          for (int r = 0; r < 8; ++r) {
            int c = (int)((r < 4 ? (zlo >> (8*r)) : (zhi >> (8*(r-4)))) & 255u);
            g[r] = (unsigned)__builtin_amdgcn_ds_bpermute(c << 2, vcur);
          }
          unsigned b0[4], b1[4];
#pragma unroll
          for (int p = 0; p < 4; ++p) {
            b0[p] = __builtin_amdgcn_perm(g[2*p+1], g[2*p], 0x05040100u);
            b1[p] = __builtin_amdgcn_perm(g[2*p+1], g[2*p], 0x07060302u);
          }
          short8 B0 = *reinterpret_cast<short8*>(b0);
          short8 B1 = *reinterpret_cast<short8*>(b1);
#pragma unroll
          for (int mr = 0; mr < 4; ++mr)
            acc[mr][ct] = __builtin_amdgcn_mfma_f32_32x32x16_bf16(af[0][mr], B0, acc[mr][ct], 0, 0, 0);
#pragma unroll
          for (int mr = 0; mr < 4; ++mr)
            acc[mr][ct] = __builtin_amdgcn_mfma_f32_32x32x16_bf16(af[1][mr], B1, acc[mr][ct], 0, 0, 0);
        }
      }
    }
  }

  // ---- fused epilogue ----
  // C/D 32x32: col = lane&31, row = (r&3) + 8*(r>>2) + 4*(lane>>5)
#pragma unroll
  for (int ct = 0; ct < 2; ++ct) {
    const int m = m0 + ct*32 + lc;
    float se = 0.f, en = 0.f;
#pragma unroll
    for (int mr = 0; mr < 4; ++mr) {
#pragma unroll
      for (int r = 0; r < 16; ++r) {
        int row = wrow + mr*32 + (r & 3) + 8*(r >> 2) + 4*lo;
        float g = acc[mr][ct][r];
        se += __expf(g);
        en += (Z1[row*MM + m] == a_blk) ? g : 0.f;
      }
    }
    se += __shfl_xor(se, 32);
    en += __shfl_xor(en, 32);
    if (lo == 0) {
      atomicAdd(&Sexp[m], se);
      atomicAdd(&Ene[m], en);
    }
  }
}

// Kernel 4: pl = -sum_m w[m]*(Ene[m] - log(Sexp[m] + 235)); block 16 adds reg term.
__global__ void k_final(const float* __restrict__ Sexp, const float* __restrict__ Ene,
                        const float* __restrict__ wts, const float* __restrict__ Mmat,
                        const float* __restrict__ Vf, float* __restrict__ out) {
  __shared__ float r4[4];
  float val = 0.f;
  if (blockIdx.x < 16) {
    int m = blockIdx.x * 256 + threadIdx.x;
    val = -wts[m] * (Ene[m] - logf(Sexp[m] + 235.0f));
  } else {
    int t = threadIdx.x;
    if (t < 64) {
      int h = t >> 3, k = t & 7;
      float dot = 0.f;
      for (int x = 0; x < Q1c*Q2c; ++x) dot += Vf[h*(Q1c*Q2c)+x] * Vf[k*(Q1c*Q2c)+x];
      int hh = (h < k) ? h : k;
      int kk = (h < k) ? k : h;
      int idx = hh*8 - (hh*(hh-1))/2 + (kk - hh);   // upper-tri index
      val = 0.001f * Mmat[idx] * dot;               // LAMBD = 0.001
    }
  }
#pragma unroll
  for (int o = 32; o; o >>= 1) val += __shfl_xor(val, o);
  int w = threadIdx.x >> 6;
  if ((threadIdx.x & 63) == 0) r4[w] = val;
  __syncthreads();
  if (threadIdx.x == 0) atomicAdd(out, r4[0] + r4[1] + r4[2] + r4[3]);
}

extern "C" void kernel_launch(void* const* d_in, const int* in_sizes, int n_in,
                              void* d_out, int out_size, void* d_ws, size_t ws_size,
                              hipStream_t stream) {
  const float* Q   = (const float*)d_in[0];
  const float* K   = (const float*)d_in[1];
  const float* V   = (const float*)d_in[2];
  const int*   Z1  = (const int*)d_in[3];
  const int*   Z2  = (const int*)d_in[4];
  const float* wts = (const float*)d_in[5];
  float* out = (float*)d_out;

  char* ws = (char*)d_ws;
  float*          sf   = (float*)ws;                               // 2 MB
  unsigned short* sfF  = (unsigned short*)(ws + (2u << 20));       // 1 MB
  unsigned char*  Z2t  = (unsigned char*)(ws + (3u << 20));        // 1 MB
  float*          Sexp = (float*)(ws + (4u << 20));                // 16 KB
  float*          Ene  = (float*)(ws + (4u << 20) + (16u << 10));  // 16 KB
  float*          Mmat = (float*)(ws + (4u << 20) + (32u << 10));  // 36 floats

  hipMemsetAsync(out, 0, sizeof(float), stream);
  hipMemsetAsync(ws + (4u << 20), 0, (32u << 10) + 256, stream);

  k_pack   <<<dim3(512),  dim3(256), 0, stream>>>(Z2, Z2t);
  k_softmax<<<dim3(2048), dim3(256), 0, stream>>>(Q, K, sf, sfF);
  k_mmat   <<<dim3(256),  dim3(256), 0, stream>>>(sf, Mmat);
  k_gemm   <<<dim3(1344), dim3(128), 0, stream>>>(sfF, V, Z1, Z2t, Sexp, Ene);
  k_final  <<<dim3(17),   dim3(256), 0, stream>>>(Sexp, Ene, wts, Mmat, V, out);
}